// Round 16
// baseline (436.346 us; speedup 1.0000x reference)
//
#include <hip/hip_runtime.h>
#include <stdint.h>

#define N_TOK 256
#define D_MODEL 1024
#define VOCAB 128000
#define NV_ELEMS (256LL * 128000LL)
#define KCAP 24576          // in-LDS key list cap (96 KB)
#define TIE_ALL 0xFFFFFFFFu

typedef unsigned long long u64;
typedef uint32_t u32;
typedef __attribute__((ext_vector_type(8))) short bfrag;   // 8 bf16 (4 VGPR)
typedef __attribute__((ext_vector_type(4))) float facc;    // 4 f32

// ===================== helpers =====================
__device__ __forceinline__ uint32_t bf16_rne_bits(float x) {
    uint32_t u = __float_as_uint(x);
    return (u + 0x7fffu + ((u >> 16) & 1u)) >> 16;
}

__device__ __forceinline__ uint32_t rotl32(uint32_t x, int d) {
    return (x << d) | (x >> (32 - d));
}

// monotone key for f32 bits (order-preserving over all finite floats)
__device__ __forceinline__ u32 mono32(u32 b) {
    return (b & 0x80000000u) ? ~b : (b | 0x80000000u);
}
__device__ __forceinline__ float unmono32(u32 k) {
    u32 b = (k & 0x80000000u) ? (k & 0x7FFFFFFFu) : ~k;
    return __uint_as_float(b);
}

// fixed-point mass: rv * 2^30 (u64). order-independent integer sums.
__device__ __forceinline__ u64 fixmass(float rv) {
    return (u64)(rv * 1073741824.0f);
}

// JAX threefry2x32, key=(0,42) (KAT-verified core)
__device__ __forceinline__ uint2 tf_0_42(uint32_t c0, uint32_t c1) {
    const uint32_t ks0 = 0u, ks1 = 42u, ks2 = 0x1BD11BDAu ^ 42u;
    uint32_t x0 = c0 + ks0, x1 = c1 + ks1;
#define R4(a,b,c,d) \
    x0 += x1; x1 = rotl32(x1,a); x1 ^= x0; \
    x0 += x1; x1 = rotl32(x1,b); x1 ^= x0; \
    x0 += x1; x1 = rotl32(x1,c); x1 ^= x0; \
    x0 += x1; x1 = rotl32(x1,d); x1 ^= x0;
    R4(13,15,26,6)   x0 += ks1; x1 += ks2 + 1u;
    R4(17,29,16,24)  x0 += ks2; x1 += ks0 + 2u;
    R4(13,15,26,6)   x0 += ks0; x1 += ks1 + 3u;
    R4(17,29,16,24)  x0 += ks1; x1 += ks2 + 4u;
    R4(13,15,26,6)   x0 += ks2; x1 += ks0 + 5u;
#undef R4
    return make_uint2(x0, x1);
}

// partitionable threefry bits: counter=(0,j), out = x^y (verified r3)
__device__ __forceinline__ uint32_t jax_bits(uint32_t j) {
    uint2 r = tf_0_42(0u, j);
    return r.x ^ r.y;
}

__device__ __forceinline__ float jax_gumbel(uint32_t bits) {
    const float TINY = 1.17549435e-38f;
    float u = __uint_as_float((bits >> 9) | 0x3f800000u) - 1.0f;
    u = u + TINY;
    u = fmaxf(TINY, u);
    return -__logf(-__logf(u));
}

__device__ __forceinline__ float rv_of(float l, float rinv) {
    return __expf(l * rinv);
}

// async 16B global->LDS (dest = lbase + lane*16)
__device__ __forceinline__ void async_copy16(const void* g, void* lbase, int lane) {
#if defined(__has_builtin) && __has_builtin(__builtin_amdgcn_global_load_lds)
    __builtin_amdgcn_global_load_lds((const uint32_t*)g, (uint32_t*)lbase, 16, 0, 0);
#else
    *(bfrag*)((char*)lbase + lane * 16) = *(const bfrag*)g;
#endif
}

// descending-bucket scan, one wave (lanes 0..63), exact u64 arithmetic
__device__ __forceinline__ void scan_desc_u64(const u64* h, int nb, u64 carry, u64 P,
                                              int* outCb, u64* outSa) {
    int lane = (int)threadIdx.x & 63;
    int chunk = nb >> 6;
    int top = nb - 1 - lane * chunk;
    u64 ls = 0ull;
    for (int j = 0; j < chunk; ++j) ls += h[top - j];
    u64 incl = ls;
    for (int o = 1; o < 64; o <<= 1) {
        u64 v = __shfl_up(incl, o, 64);
        if (lane >= o) incl += v;
    }
    u64 s0 = carry + incl - ls;
    unsigned long long mask = __ballot(s0 + ls > P);
    if (mask == 0ull) {
        if (lane == 0) { *outCb = 0; *outSa = carry; }   // cannot happen (P < total)
    } else {
        int cstar = (int)__builtin_ctzll(mask);
        if (lane == cstar) {
            u64 sa = s0; int cb = 0;
            for (int j = 0; j < chunk; ++j) {
                int b = top - j;
                if (sa + h[b] > P) { cb = b; break; }
                sa += h[b];
            }
            *outCb = cb; *outSa = sa;
        }
    }
}

// ============ A pre-convert (gather + split-bf16 + swizzled image, BK=32) ====
__global__ __launch_bounds__(256) void prep_a(
        const float* __restrict__ hidden, const int* __restrict__ idx,
        ushort* __restrict__ wsA) {
    const int m = blockIdx.x;
    const int t = threadIdx.x;
    const float* src = hidden + (long long)idx[m] * D_MODEL;
    const uint32_t swz = (uint32_t)((m & 7) << 4);
    for (int j = 0; j < 4; ++j) {
        int k = t * 4 + j;
        float x = src[k];
        uint32_t hb = bf16_rne_bits(x);
        float hf = __uint_as_float(hb << 16);
        uint32_t lb = bf16_rne_bits(x - hf);
        int kt = k >> 5, kk = k & 31, g = kk >> 3, e = kk & 7;
        char* img = (char*)wsA + (size_t)kt * 32768;
        uint32_t base = (uint32_t)(m * 128 + g * 32);
        *(ushort*)(img + ((base + 0) ^ swz) + e * 2) = (ushort)hb;
        *(ushort*)(img + ((base + 16) ^ swz) + e * 2) = (ushort)lb;
    }
}

// ===== split-bf16 MFMA GEMM — r5/r10/r13 measured-best (BM=256,BN=64,BK=32,
// 4 waves, 40 KB LDS; 894 TF-equiv = the 2-barrier structural ceiling) =====
__global__ __launch_bounds__(256) void gemm_mfma(
        const ushort* __restrict__ wsA, const float* __restrict__ emb,
        float* __restrict__ logits) {
    __shared__ __align__(16) ushort Aimg[16384];  // 32 KB swizzled A K-tile
    __shared__ __align__(16) ushort Bimg[4096];   // 8 KB swizzled B K-tile
    const int tid = (int)threadIdx.x;
    const int w = tid >> 6, l = tid & 63;
    const int lr = l & 15, lg = l >> 4;
    const int v0 = blockIdx.x * 64;
    char* Ab = (char*)Aimg;
    char* Bb = (char*)Bimg;

    facc acc[4][4] = {};

    for (int kt = 0; kt < 32; ++kt) {
        __syncthreads();
        const char* asrc = (const char*)wsA + (size_t)kt * 32768;
#pragma unroll
        for (int i = 0; i < 8; ++i) {
            int off = w * 8192 + i * 1024;
            async_copy16(asrc + off + l * 16, Ab + off, l);
        }
        {
            int rb = tid >> 2, g = tid & 3;
            const float* bs = emb + (size_t)(v0 + rb) * D_MODEL + kt * 32 + g * 8;
            float4 x0 = *(const float4*)bs;
            float4 x1 = *(const float4*)(bs + 4);
            float xs[8] = {x0.x, x0.y, x0.z, x0.w, x1.x, x1.y, x1.z, x1.w};
            bfrag h, lo;
#pragma unroll
            for (int e = 0; e < 8; ++e) {
                uint32_t hb = bf16_rne_bits(xs[e]);
                float hf = __uint_as_float(hb << 16);
                uint32_t lb = bf16_rne_bits(xs[e] - hf);
                h[e] = (short)hb; lo[e] = (short)lb;
            }
            uint32_t swz = (uint32_t)((rb & 7) << 4);
            uint32_t base = (uint32_t)(rb * 128 + g * 32);
            *(bfrag*)(Bb + ((base + 0) ^ swz)) = h;
            *(bfrag*)(Bb + ((base + 16) ^ swz)) = lo;
        }
        __syncthreads();
        bfrag bh[4], bl[4];
#pragma unroll
        for (int nj = 0; nj < 4; ++nj) {
            int rb = nj * 16 + lr;
            uint32_t swz = (uint32_t)((rb & 7) << 4);
            uint32_t base = (uint32_t)(rb * 128 + lg * 32);
            bh[nj] = *(const bfrag*)(Bb + ((base + 0) ^ swz));
            bl[nj] = *(const bfrag*)(Bb + ((base + 16) ^ swz));
        }
#pragma unroll
        for (int mi = 0; mi < 4; ++mi) {
            int r = w * 64 + mi * 16 + lr;
            uint32_t swz = (uint32_t)((r & 7) << 4);
            uint32_t base = (uint32_t)(r * 128 + lg * 32);
            bfrag ah = *(const bfrag*)(Ab + ((base + 0) ^ swz));
            bfrag al = *(const bfrag*)(Ab + ((base + 16) ^ swz));
#pragma unroll
            for (int nj = 0; nj < 4; ++nj) {
                acc[mi][nj] = __builtin_amdgcn_mfma_f32_16x16x32_bf16(ah, bh[nj], acc[mi][nj], 0, 0, 0);
                acc[mi][nj] = __builtin_amdgcn_mfma_f32_16x16x32_bf16(ah, bl[nj], acc[mi][nj], 0, 0, 0);
                acc[mi][nj] = __builtin_amdgcn_mfma_f32_16x16x32_bf16(al, bh[nj], acc[mi][nj], 0, 0, 0);
            }
        }
    }
#pragma unroll
    for (int mi = 0; mi < 4; ++mi) {
        int mbase = w * 64 + mi * 16 + lg * 4;
#pragma unroll
        for (int nj = 0; nj < 4; ++nj) {
            int v = v0 + nj * 16 + lr;
#pragma unroll
            for (int reg = 0; reg < 4; ++reg)
                logits[(size_t)(mbase + reg) * VOCAB + v] = acc[mi][nj][reg];
        }
    }
}

// ===================== f32 GEMM fallback (ws too small) =====================
__global__ __launch_bounds__(256) void gemm_kernel(
        const float* __restrict__ hidden, const int* __restrict__ idx,
        const float* __restrict__ emb, float* __restrict__ logits) {
    __shared__ float As[16][64];
    __shared__ float Bs[16][64];
    const int n0 = blockIdx.x * 64, v0 = blockIdx.y * 64;
    const int tid = threadIdx.x;
    const int tx = tid & 15, ty = tid >> 4;
    const int lr = tid >> 2, lk = (tid & 3) * 4;
    float acc[4][4] = {};
    const long long aRow = (long long)idx[n0 + lr] * D_MODEL + lk;
    const long long bRow = (long long)(v0 + lr) * D_MODEL + lk;
    for (int k0 = 0; k0 < D_MODEL; k0 += 16) {
        float4 av = *(const float4*)(hidden + aRow + k0);
        float4 bv = *(const float4*)(emb + bRow + k0);
        __syncthreads();
        As[lk + 0][lr] = av.x; As[lk + 1][lr] = av.y; As[lk + 2][lr] = av.z; As[lk + 3][lr] = av.w;
        Bs[lk + 0][lr] = bv.x; Bs[lk + 1][lr] = bv.y; Bs[lk + 2][lr] = bv.z; Bs[lk + 3][lr] = bv.w;
        __syncthreads();
#pragma unroll
        for (int kk = 0; kk < 16; ++kk) {
            float4 a = *(const float4*)&As[kk][ty * 4];
            float4 b = *(const float4*)&Bs[kk][tx * 4];
            float aa[4] = {a.x, a.y, a.z, a.w};
            float bb[4] = {b.x, b.y, b.z, b.w};
#pragma unroll
            for (int i = 0; i < 4; ++i)
#pragma unroll
                for (int j = 0; j < 4; ++j)
                    acc[i][j] += aa[i] * bb[j];
        }
    }
#pragma unroll
    for (int i = 0; i < 4; ++i) {
        float4 o = make_float4(acc[i][0], acc[i][1], acc[i][2], acc[i][3]);
        *(float4*)(logits + (long long)(n0 + ty * 4 + i) * VOCAB + (v0 + tx * 4)) = o;
    }
}

// ========== sampleRow: FULLY FUSED per-row sampler ==========
// Per row: L1 hist (4-replica) -> scan; L2 hist + ballot-compacted key list
// -> scan; L3 from LDS list (row-pass fallback if >KCAP) -> ts/mt/Sp; in-LDS
// tie ranks; final pass writes probs_f + gumbel-argmax; direct token store.
// No workspace, no cross-block state; all math = r13-verified exact u64.
__global__ __launch_bounds__(1024) void sampleRow_kernel(
        float* __restrict__ probs, const float* __restrict__ temps,
        const float* __restrict__ topps, float* __restrict__ outTok) {
    const int row = blockIdx.x, tid = (int)threadIdx.x;
    __shared__ u64 hrep[4][4096];           // 128 KB; pass-B arrays alias it
    __shared__ u32 tlist[1024];
    __shared__ u64 wredu[16];
    __shared__ float aVal[16];
    __shared__ int aIdx[16];
    __shared__ int sCb; __shared__ u64 sSa;
    __shared__ u64 sP;
    __shared__ u32 sCb1; __shared__ u64 sCarry1;
    __shared__ u32 sCb2; __shared__ u64 sCarry2;
    __shared__ u32 sListCnt, sTc, sTsKey, sMt, sCntb;
    __shared__ float sInv;

    u32* klist = (u32*)&hrep[0][0];                       // 96 KB
    u64* h2    = (u64*)((char*)&hrep[0][0] + 98304);      // 8 KB
    u32* c3    = (u32*)((char*)&hrep[0][0] + 106496);     // 4 KB

    const float rinv = 1.0f / temps[row];
    float* L = probs + (size_t)row * VOCAB;
    const float4* R4 = (const float4*)L;
    float4* W4 = (float4*)L;
    const int lane = tid & 63;

    // ---- pass A: L1 hist, bucket = key >> 20, 4 replicas by wave
    for (int i = tid; i < 16384; i += 1024) ((u64*)hrep)[i] = 0ull;
    __syncthreads();
    {
        u64* myrep = hrep[(tid >> 6) & 3];
        for (int i = 0; i < 32; ++i) {
            int j = tid + i * 1024;
            if (j < 32000) {
                float4 x = R4[j];
                float xs[4] = {x.x, x.y, x.z, x.w};
#pragma unroll
                for (int c = 0; c < 4; ++c) {
                    u32 key = mono32(__float_as_uint(xs[c]));
                    atomicAdd(&myrep[key >> 20], fixmass(rv_of(xs[c], rinv)));
                }
            }
        }
    }
    __syncthreads();
    for (int b = tid; b < 4096; b += 1024)
        hrep[0][b] += hrep[1][b] + hrep[2][b] + hrep[3][b];
    __syncthreads();
    {
        u64 s = hrep[0][tid] + hrep[0][tid + 1024] + hrep[0][tid + 2048] + hrep[0][tid + 3072];
        for (int o = 32; o >= 1; o >>= 1) s += __shfl_xor(s, o, 64);
        if (lane == 0) wredu[tid >> 6] = s;
    }
    __syncthreads();
    if (tid == 0) {
        u64 S = 0ull;
        for (int w2 = 0; w2 < 16; ++w2) S += wredu[w2];
        sP = (u64)((double)topps[row] * (double)S);
    }
    __syncthreads();
    const u64 P = sP;
    if (tid < 64) scan_desc_u64(hrep[0], 4096, 0ull, P, &sCb, &sSa);
    __syncthreads();
    if (tid == 0) { sCb1 = (u32)sCb; sCarry1 = sSa; sListCnt = 0u; }
    __syncthreads();
    const u32 cb1 = sCb1;
    h2[tid] = 0ull; c3[tid] = 0u;
    __syncthreads();

    // ---- pass B: L2 hist + ballot-compacted key list of the cut L1 bucket
    for (int i = 0; i < 32; ++i) {
        int j = tid + i * 1024;
        bool valid = j < 32000;
        float4 x = valid ? R4[j] : make_float4(0.f, 0.f, 0.f, 0.f);
        float xs[4] = {x.x, x.y, x.z, x.w};
#pragma unroll
        for (int c = 0; c < 4; ++c) {
            u32 key = mono32(__float_as_uint(xs[c]));
            bool m = valid && ((key >> 20) == cb1);
            if (m) atomicAdd(&h2[(key >> 10) & 1023u], fixmass(rv_of(xs[c], rinv)));
            unsigned long long grp = __ballot(m);
            if (m) {
                u32 prefix = (u32)__popcll(grp & ((1ull << lane) - 1ull));
                int leader = (int)__builtin_ctzll(grp);
                u32 base = 0u;
                if (lane == leader) base = atomicAdd(&sListCnt, (u32)__popcll(grp));
                base = (u32)__shfl((int)base, leader, 64);
                u32 pos = base + prefix;
                if (pos < KCAP) klist[pos] = key;
            }
        }
    }
    __syncthreads();
    const u32 listTotal = sListCnt;
    const bool inLds = listTotal <= (u32)KCAP;
    if (tid < 64) scan_desc_u64(h2, 1024, sCarry1, P, &sCb, &sSa);
    __syncthreads();
    if (tid == 0) { sCb2 = (u32)sCb; sCarry2 = sSa; }
    __syncthreads();
    const u32 cb2 = sCb2;
    const u32 pref2 = (cb1 << 10) | cb2;
    h2[tid] = 0ull; c3[tid] = 0u;
    __syncthreads();

    // ---- L3 hist: from the in-LDS list (common) or a 3rd row pass (fallback)
    if (inLds) {
        for (u32 q = tid; q < listTotal; q += 1024) {
            u32 key = klist[q];
            if ((key >> 10) == pref2) {
                atomicAdd(&h2[key & 1023u], fixmass(rv_of(unmono32(key), rinv)));
                atomicAdd(&c3[key & 1023u], 1u);
            }
        }
    } else {
        for (int i = 0; i < 32; ++i) {
            int j = tid + i * 1024;
            if (j < 32000) {
                float4 x = R4[j];
                float xs[4] = {x.x, x.y, x.z, x.w};
#pragma unroll
                for (int c = 0; c < 4; ++c) {
                    u32 key = mono32(__float_as_uint(xs[c]));
                    if ((key >> 10) == pref2) {
                        atomicAdd(&h2[key & 1023u], fixmass(rv_of(xs[c], rinv)));
                        atomicAdd(&c3[key & 1023u], 1u);
                    }
                }
            }
        }
    }
    __syncthreads();
    if (tid < 64) scan_desc_u64(h2, 1024, sCarry2, P, &sCb, &sSa);
    __syncthreads();
    if (tid == 0) {
        const int cb3 = sCb; const u64 sa3 = sSa;
        u32 ts = (pref2 << 10) | (u32)cb3;
        u32 cntb = c3[cb3]; if (cntb == 0u) cntb = 1u;
        u64 tfq = fixmass(rv_of(unmono32(ts), rinv));
        u64 rem = P - sa3;
        u32 mt;
        if (tfq == 0ull) mt = cntb;
        else {
            u64 q = rem / tfq;
            mt = (q >= (u64)(cntb - 1)) ? cntb : ((u32)q + 1u);
        }
        u64 Spq = sa3 + (u64)mt * tfq;
        sTsKey = ts; sMt = mt; sCntb = cntb;
        sInv = (float)(1073741824.0 / (double)Spq);
        sTc = 0u;
    }
    __syncthreads();
    const u32 ts = sTsKey, mt = sMt, cntb = sCntb;

    // ---- tie ranking (rare): only when the cut splits a bit-identical group
    u32 tn = 0u;
    const bool tieSplit = (mt < cntb);
    if (tieSplit) {
        for (int i = 0; i < 32; ++i) {
            int j = tid + i * 1024;
            if (j < 32000) {
                float4 x = R4[j];
                float xs[4] = {x.x, x.y, x.z, x.w};
#pragma unroll
                for (int c = 0; c < 4; ++c) {
                    u32 key = mono32(__float_as_uint(xs[c]));
                    if (key == ts) {
                        u32 pos = atomicAdd(&sTc, 1u);
                        if (pos < 1024u) tlist[pos] = (u32)(j * 4 + c);
                    }
                }
            }
        }
        __syncthreads();
        tn = min(sTc, 1024u);
    }

    // ---- final pass: write probs_f + gumbel-argmax (tie rank via tlist)
    const float invSp = sInv;
    const u32 rowBase = (u32)row * (u32)VOCAB;
    float bestV = -INFINITY;
    int bestI = 0x7FFFFFFF;
    for (int i = 0; i < 32; ++i) {
        int j = tid + i * 1024;
        if (j < 32000) {
            float4 x = R4[j];
            float xs[4] = {x.x, x.y, x.z, x.w};
            float4 out;
            float* op = (float*)&out;
#pragma unroll
            for (int c = 0; c < 4; ++c) {
                u32 key = mono32(__float_as_uint(xs[c]));
                u32 v = (u32)(j * 4 + c);
                bool kept = key > ts;
                if (key == ts) {
                    if (!tieSplit) {
                        kept = true;
                    } else {
                        u32 rank = 0;
                        for (u32 j2 = 0; j2 < tn; ++j2)
                            rank += (tlist[j2] < v) ? 1u : 0u;
                        kept = rank < mt;
                    }
                }
                if (kept) {
                    float pf = rv_of(xs[c], rinv) * invSp;
                    op[c] = pf;
                    float g = jax_gumbel(jax_bits(rowBase + v));
                    float val = __logf(pf + 1e-20f) + g;
                    if (val > bestV || (val == bestV && (int)v < bestI)) {
                        bestV = val; bestI = (int)v;
                    }
                } else {
                    op[c] = 0.0f;
                }
            }
            W4[j] = out;
        }
    }
    // block argmax reduce (value, then lowest index)
    for (int o = 32; o >= 1; o >>= 1) {
        float ov = __shfl_xor(bestV, o, 64);
        int oi = __shfl_xor(bestI, o, 64);
        if (ov > bestV || (ov == bestV && oi < bestI)) { bestV = ov; bestI = oi; }
    }
    if (lane == 0) { aVal[tid >> 6] = bestV; aIdx[tid >> 6] = bestI; }
    __syncthreads();
    if (tid == 0) {
        float bv = aVal[0]; int bi = aIdx[0];
        for (int w2 = 1; w2 < 16; ++w2) {
            if (aVal[w2] > bv || (aVal[w2] == bv && aIdx[w2] < bi)) {
                bv = aVal[w2]; bi = aIdx[w2];
            }
        }
        outTok[row] = (float)bi;
    }
}

// ===================== launch =====================
extern "C" void kernel_launch(void* const* d_in, const int* in_sizes, int n_in,
                              void* d_out, int out_size, void* d_ws, size_t ws_size,
                              hipStream_t stream) {
    const float* hidden = (const float*)d_in[0];
    const float* emb    = (const float*)d_in[1];
    const float* temps  = (const float*)d_in[2];
    const float* topps  = (const float*)d_in[3];
    const int*   idx    = (const int*)d_in[4];

    float* probs  = (float*)d_out;        // [N,V]: logits, then probs_f in place
    float* outTok = probs + NV_ELEMS;     // [N] tokens as f32

    char* ws = (char*)d_ws;
    const bool wsGemm = ws_size >= (size_t)(1u << 20);

    if (wsGemm) {
        ushort* wsA = (ushort*)ws;        // 32 x 32 KB pre-swizzled A images
        prep_a<<<N_TOK, 256, 0, stream>>>(hidden, idx, wsA);
        gemm_mfma<<<VOCAB / 64, 256, 0, stream>>>(wsA, emb, probs);
    } else {
        gemm_kernel<<<dim3(4, 2000), 256, 0, stream>>>(hidden, idx, emb, probs);
    }

    sampleRow_kernel<<<N_TOK, 1024, 0, stream>>>(probs, temps, topps, outTok);
}